// Round 1
// baseline (1128.099 us; speedup 1.0000x reference)
//
#include <hip/hip_runtime.h>
#include <hip/hip_bf16.h>

#define BB 128
#define NN 512
#define DD 256
#define NT 6
#define NS 8

__device__ __forceinline__ float wave_sum(float v) {
#pragma unroll
  for (int o = 32; o > 0; o >>= 1) v += __shfl_xor(v, o);
  return v;
}

__global__ void k_init(int* wsi) {
  if (threadIdx.x < 8) wsi[threadIdx.x] = 0;
}

__global__ void k_counts(const int* __restrict__ msk, int* __restrict__ wsi) {
  const int b = blockIdx.x;
  int cnt = 0;
  for (int i = threadIdx.x; i < NN; i += blockDim.x) cnt += (msk[b * NN + i] != 0) ? 1 : 0;
  float s = wave_sum((float)cnt);
  __shared__ float red[4];
  const int lane = threadIdx.x & 63, wv = threadIdx.x >> 6;
  if (lane == 0) red[wv] = s;
  __syncthreads();
  if (threadIdx.x == 0) {
    int k = (int)(red[0] + red[1] + red[2] + red[3] + 0.5f);
    atomicAdd(&wsi[4], k);
    atomicAdd(&wsi[5], NN * NN - (NN - k) * (NN - k));
  }
}

// ---- heads kernel: 64 rows per block, 256 threads ----
__global__ __launch_bounds__(256) void k_heads(
    const float* __restrict__ x, const int* __restrict__ msk,
    const int* __restrict__ tgt, const float* __restrict__ stats,
    const float* __restrict__ Wt1, const float* __restrict__ bt1,
    const float* __restrict__ gt, const float* __restrict__ blt,
    const float* __restrict__ Wt2, const float* __restrict__ bt2,
    const float* __restrict__ Ws1, const float* __restrict__ bs1,
    const float* __restrict__ gs, const float* __restrict__ bls,
    const float* __restrict__ Ws2, const float* __restrict__ bs2,
    float* __restrict__ fs)
{
  const int tid = threadIdx.x;
  const int row0 = blockIdx.x * 64;
  __shared__ float xs[64 * 256];       // x tile, broadcast-read only
  __shared__ float hs[64 * 260];       // h tile, padded (+4) for LN/phase-C reads
  __shared__ float lg[64 * 8];         // logits / preds

  // load 64 contiguous rows of x
  {
    const float4* src = (const float4*)(x + (size_t)row0 * DD);
    float4* dst = (float4*)xs;
    for (int i = tid; i < 64 * 64; i += 256) dst[i] = src[i];
  }
  __syncthreads();

  const int cg = tid & 63, c0 = cg * 4;  // column group: 4 cols per thread
  const int rg = tid >> 6, r0 = rg * 16; // row group: 16 rows per thread (wave-uniform)
  const int lane = tid & 63, wv = tid >> 6;

  for (int head = 0; head < 2; ++head) {
    const float* W1 = head ? Ws1 : Wt1;
    const float* b1 = head ? bs1 : bt1;
    const float* g  = head ? gs  : gt;
    const float* be = head ? bls : blt;
    const float* W2 = head ? Ws2 : Wt2;
    const float* b2 = head ? bs2 : bt2;
    const int C2 = head ? NS : NT;

    // phase A: h = gelu(x @ W1 + b1); thread computes 16 rows x 4 cols
    float acc[16][4];
#pragma unroll
    for (int i = 0; i < 16; ++i)
#pragma unroll
      for (int j = 0; j < 4; ++j) acc[i][j] = 0.0f;

    for (int d = 0; d < DD; d += 4) {
      float w0[4], w1[4], w2[4], w3[4];
      *(float4*)w0 = *(const float4*)&W1[(d + 0) * DD + c0];
      *(float4*)w1 = *(const float4*)&W1[(d + 1) * DD + c0];
      *(float4*)w2 = *(const float4*)&W1[(d + 2) * DD + c0];
      *(float4*)w3 = *(const float4*)&W1[(d + 3) * DD + c0];
#pragma unroll
      for (int i = 0; i < 16; ++i) {
        float4 xv = *(const float4*)&xs[(r0 + i) * DD + d];  // wave-broadcast
#pragma unroll
        for (int j = 0; j < 4; ++j)
          acc[i][j] += xv.x * w0[j] + xv.y * w1[j] + xv.z * w2[j] + xv.w * w3[j];
      }
    }
    {
      float bb[4];
      *(float4*)bb = *(const float4*)&b1[c0];
#pragma unroll
      for (int i = 0; i < 16; ++i) {
        float hv[4];
#pragma unroll
        for (int j = 0; j < 4; ++j) {
          float h = acc[i][j] + bb[j];
          hv[j] = 0.5f * h * (1.0f + erff(h * 0.70710678118654752f));  // exact GELU
        }
        *(float4*)&hs[(r0 + i) * 260 + c0] = *(float4*)hv;
      }
    }
    __syncthreads();

    // LN: each wave owns 16 rows; 64 lanes x 4 values per row
    for (int rr = 0; rr < 16; ++rr) {
      int r = wv * 16 + rr;
      float hv[4];
      *(float4*)hv = *(const float4*)&hs[r * 260 + lane * 4];
      float s  = hv[0] + hv[1] + hv[2] + hv[3];
      float ss = hv[0]*hv[0] + hv[1]*hv[1] + hv[2]*hv[2] + hv[3]*hv[3];
      s = wave_sum(s);
      ss = wave_sum(ss);
      float mu  = s * (1.0f / DD);
      float var = ss * (1.0f / DD) - mu * mu;
      float rstd = rsqrtf(var + 1e-5f);
      int c = lane * 4;
      float gv[4], bv[4];
      *(float4*)gv = *(const float4*)&g[c];
      *(float4*)bv = *(const float4*)&be[c];
#pragma unroll
      for (int j = 0; j < 4; ++j) hv[j] = (hv[j] - mu) * rstd * gv[j] + bv[j];
      *(float4*)&hs[r * 260 + lane * 4] = *(float4*)hv;
    }
    __syncthreads();

    // phase C: small second linear -> lg
    for (int p = tid; p < 64 * C2; p += 256) {
      int r = p / C2, c = p % C2;
      float a = b2[c];
      for (int k = 0; k < DD; k += 4) {
        float4 hv = *(const float4*)&hs[r * 260 + k];
        a += hv.x * W2[(k + 0) * C2 + c] + hv.y * W2[(k + 1) * C2 + c] +
             hv.z * W2[(k + 2) * C2 + c] + hv.w * W2[(k + 3) * C2 + c];
      }
      lg[r * 8 + c] = a;
    }
    __syncthreads();

    // loss: one lane per row (wave 0)
    if (tid < 64) {
      int grow = row0 + tid;
      int mbit = msk[grow];
      float contrib = 0.0f;
      if (head == 0) {
        float l[NT];
        float mx = -1e30f;
#pragma unroll
        for (int c = 0; c < NT; ++c) { l[c] = lg[tid * 8 + c]; mx = fmaxf(mx, l[c]); }
        float se = 0.0f;
#pragma unroll
        for (int c = 0; c < NT; ++c) se += expf(l[c] - mx);
        float lse = mx + logf(se);
        int t = tgt[grow];
        contrib = mbit ? (lse - l[t]) : 0.0f;
      } else {
        const float* st = stats + (size_t)grow * NS;
        float sse = 0.0f;
#pragma unroll
        for (int c = 0; c < NS; ++c) {
          float d2 = lg[tid * 8 + c] - st[c];
          sse += d2 * d2;
        }
        contrib = mbit ? sse : 0.0f;
      }
      float s = wave_sum(contrib);
      if (tid == 0) atomicAdd(&fs[head], s);
    }
    __syncthreads();
  }
}

// ---- correlation kernel: one block per (batch, 64-row i-tile) ----
__global__ __launch_bounds__(256) void k_corr(
    const float* __restrict__ x, const int* __restrict__ msk,
    const float* __restrict__ corr, const float* __restrict__ Wc,
    const float* __restrict__ bcp, float* __restrict__ fs)
{
  const int tid = threadIdx.x;
  const int b = blockIdx.x >> 3;
  const int it = blockIdx.x & 7;
  const int i0 = it * 64;
  __shared__ float xs[64 * 260];  // padded: phase-B reads 16 distinct rows/wave
  __shared__ float ys[64 * 260];
  __shared__ int ms_i[64], ms_j[64];
  __shared__ float red[4];

  const float* xb = x + (size_t)b * NN * DD;

  // load i-tile
  {
    const float* src = xb + (size_t)i0 * DD;
    for (int idx = tid; idx < 64 * 64; idx += 256) {
      int r = idx >> 6, c4 = idx & 63;
      *(float4*)&xs[r * 260 + c4 * 4] = *(const float4*)&src[r * DD + c4 * 4];
    }
    if (tid < 64) ms_i[tid] = msk[b * NN + i0 + tid];
  }
  __syncthreads();

  // phase A: y = x_tile @ Wc
  {
    const int cg = tid & 63, c0 = cg * 4;
    const int rg = tid >> 6, r0 = rg * 16;
    float acc[16][4];
#pragma unroll
    for (int i = 0; i < 16; ++i)
#pragma unroll
      for (int j = 0; j < 4; ++j) acc[i][j] = 0.0f;

    for (int d = 0; d < DD; d += 4) {
      float w0[4], w1[4], w2[4], w3[4];
      *(float4*)w0 = *(const float4*)&Wc[(d + 0) * DD + c0];
      *(float4*)w1 = *(const float4*)&Wc[(d + 1) * DD + c0];
      *(float4*)w2 = *(const float4*)&Wc[(d + 2) * DD + c0];
      *(float4*)w3 = *(const float4*)&Wc[(d + 3) * DD + c0];
#pragma unroll
      for (int i = 0; i < 16; ++i) {
        float4 xv = *(const float4*)&xs[(r0 + i) * 260 + d];
#pragma unroll
        for (int j = 0; j < 4; ++j)
          acc[i][j] += xv.x * w0[j] + xv.y * w1[j] + xv.z * w2[j] + xv.w * w3[j];
      }
    }
#pragma unroll
    for (int i = 0; i < 16; ++i)
      *(float4*)&ys[(r0 + i) * 260 + c0] = *(float4*)acc[i];
  }
  __syncthreads();

  const float bc = bcp[0];
  const int ti = tid >> 4;    // 0..15 (0..3 within a wave)
  const int tjj = tid & 15;   // 0..15
  float sse = 0.0f;

  for (int jt = 0; jt < 8; ++jt) {
    __syncthreads();  // previous tile fully consumed before overwrite
    {
      const float* src = xb + (size_t)(jt * 64) * DD;
      for (int idx = tid; idx < 64 * 64; idx += 256) {
        int r = idx >> 6, c4 = idx & 63;
        *(float4*)&xs[r * 260 + c4 * 4] = *(const float4*)&src[r * DD + c4 * 4];
      }
      if (tid < 64) ms_j[tid] = msk[b * NN + jt * 64 + tid];
    }
    __syncthreads();

    float a[4][4];
#pragma unroll
    for (int ii = 0; ii < 4; ++ii)
#pragma unroll
      for (int jj = 0; jj < 4; ++jj) a[ii][jj] = 0.0f;

    for (int e = 0; e < DD; e += 4) {
      float4 yv[4], xv[4];
#pragma unroll
      for (int ii = 0; ii < 4; ++ii) yv[ii] = *(const float4*)&ys[(ti + 16 * ii) * 260 + e];
#pragma unroll
      for (int jj = 0; jj < 4; ++jj) xv[jj] = *(const float4*)&xs[(tjj + 16 * jj) * 260 + e];
#pragma unroll
      for (int ii = 0; ii < 4; ++ii)
#pragma unroll
        for (int jj = 0; jj < 4; ++jj)
          a[ii][jj] += yv[ii].x * xv[jj].x + yv[ii].y * xv[jj].y +
                       yv[ii].z * xv[jj].z + yv[ii].w * xv[jj].w;
    }

#pragma unroll
    for (int ii = 0; ii < 4; ++ii) {
      int li = ti + 16 * ii;
      int gi = i0 + li;
#pragma unroll
      for (int jj = 0; jj < 4; ++jj) {
        int lj = tjj + 16 * jj;
        int gj = jt * 64 + lj;
        float s = a[ii][jj] + bc;
        float cv = (gi == gj) ? 1.0f : tanhf(s);
        float tg = corr[((size_t)b * NN + gi) * NN + gj];
        float dd = cv - tg;
        int mb = ms_i[li] | ms_j[lj];
        sse += mb ? dd * dd : 0.0f;
      }
    }
  }

  float s = wave_sum(sse);
  if ((tid & 63) == 0) red[tid >> 6] = s;
  __syncthreads();
  if (tid == 0) atomicAdd(&fs[2], red[0] + red[1] + red[2] + red[3]);
}

__global__ void k_final(const float* __restrict__ fs, const int* __restrict__ wsi,
                        float* __restrict__ out) {
  if (threadIdx.x == 0 && blockIdx.x == 0) {
    float cm = (float)wsi[4];
    float c2 = (float)wsi[5];
    out[0] = fs[0] / fmaxf(cm, 1.0f) + fs[1] / fmaxf(8.0f * cm, 1.0f) +
             0.5f * fs[2] / fmaxf(c2, 1.0f);
  }
}

extern "C" void kernel_launch(void* const* d_in, const int* in_sizes, int n_in,
                              void* d_out, int out_size, void* d_ws, size_t ws_size,
                              hipStream_t stream) {
  const float* x     = (const float*)d_in[0];
  const int*   msk   = (const int*)d_in[1];
  const int*   tgt   = (const int*)d_in[2];
  const float* stats = (const float*)d_in[3];
  const float* corr  = (const float*)d_in[4];
  const float* Wt1   = (const float*)d_in[5];
  const float* bt1   = (const float*)d_in[6];
  const float* gt    = (const float*)d_in[7];
  const float* blt   = (const float*)d_in[8];
  const float* Wt2   = (const float*)d_in[9];
  const float* bt2   = (const float*)d_in[10];
  const float* Ws1   = (const float*)d_in[11];
  const float* bs1   = (const float*)d_in[12];
  const float* gs    = (const float*)d_in[13];
  const float* bls   = (const float*)d_in[14];
  const float* Ws2   = (const float*)d_in[15];
  const float* bs2   = (const float*)d_in[16];
  const float* Wc    = (const float*)d_in[17];
  const float* bc    = (const float*)d_in[18];

  float* fs = (float*)d_ws;
  int* wsi  = (int*)d_ws;

  hipLaunchKernelGGL(k_init, dim3(1), dim3(64), 0, stream, wsi);
  hipLaunchKernelGGL(k_counts, dim3(BB), dim3(256), 0, stream, msk, wsi);
  hipLaunchKernelGGL(k_heads, dim3((BB * NN) / 64), dim3(256), 0, stream,
                     x, msk, tgt, stats, Wt1, bt1, gt, blt, Wt2, bt2,
                     Ws1, bs1, gs, bls, Ws2, bs2, fs);
  hipLaunchKernelGGL(k_corr, dim3(BB * (NN / 64)), dim3(256), 0, stream,
                     x, msk, corr, Wc, bc, fs);
  hipLaunchKernelGGL(k_final, dim3(1), dim3(64), 0, stream, fs, wsi, (float*)d_out);
}

// Round 2
// 243.601 us; speedup vs baseline: 4.6309x; 4.6309x over previous
//
#include <hip/hip_runtime.h>
#include <hip/hip_bf16.h>

#define BB 128
#define NN 512
#define DD 256

typedef __attribute__((ext_vector_type(4))) float f32x4;
typedef __attribute__((ext_vector_type(8))) short s16x8;
typedef __attribute__((ext_vector_type(8))) __bf16 bf16x8;

static __device__ __forceinline__ bf16x8 as_bf(s16x8 v) {
  return __builtin_bit_cast(bf16x8, v);
}

static __device__ __forceinline__ unsigned short f2bf(float f) {
  unsigned u = __builtin_bit_cast(unsigned, f);
  u += 0x7FFFu + ((u >> 16) & 1u);
  return (unsigned short)(u >> 16);
}

__device__ __forceinline__ float wave_sum(float v) {
#pragma unroll
  for (int o = 32; o > 0; o >>= 1) v += __shfl_xor(v, o);
  return v;
}

__global__ void k_init(int* wsi) {
  if (threadIdx.x < 8) wsi[threadIdx.x] = 0;
}

__global__ void k_counts(const int* __restrict__ msk, int* __restrict__ wsi) {
  const int b = blockIdx.x;
  int cnt = 0;
  for (int i = threadIdx.x; i < NN; i += blockDim.x) cnt += (msk[b * NN + i] != 0) ? 1 : 0;
  float s = wave_sum((float)cnt);
  __shared__ float red[4];
  const int lane = threadIdx.x & 63, wv = threadIdx.x >> 6;
  if (lane == 0) red[wv] = s;
  __syncthreads();
  if (threadIdx.x == 0) {
    int k = (int)(red[0] + red[1] + red[2] + red[3] + 0.5f);
    atomicAdd(&wsi[4], k);
    atomicAdd(&wsi[5], NN * NN - (NN - k) * (NN - k));
  }
}

// transpose + bf16-convert the weight matrices into workspace
__global__ void k_prep(const float* __restrict__ Wc, const float* __restrict__ Wt1,
                       const float* __restrict__ Ws1, const float* __restrict__ Wt2,
                       const float* __restrict__ Ws2,
                       unsigned short* __restrict__ WcT, unsigned short* __restrict__ Wt1T,
                       unsigned short* __restrict__ Ws1T, unsigned short* __restrict__ Wt2T,
                       unsigned short* __restrict__ Ws2T) {
  int t = blockIdx.x * 256 + threadIdx.x;  // 0..65535
  int c = t >> 8, d = t & 255;
  WcT [c * 256 + d] = f2bf(Wc [d * 256 + c]);
  Wt1T[c * 256 + d] = f2bf(Wt1[d * 256 + c]);
  Ws1T[c * 256 + d] = f2bf(Ws1[d * 256 + c]);
  if (c < 16) {
    Wt2T[c * 256 + d] = (c < 6) ? f2bf(Wt2[d * 6 + c]) : (unsigned short)0;
    Ws2T[c * 256 + d] = (c < 8) ? f2bf(Ws2[d * 8 + c]) : (unsigned short)0;
  }
}

// ---------------- heads: 128 rows/block, 512 threads, MFMA ----------------
__global__ __launch_bounds__(512) void k_heads(
    const float* __restrict__ x, const int* __restrict__ msk,
    const int* __restrict__ tgt, const float* __restrict__ stats,
    const unsigned short* __restrict__ Wt1T, const float* __restrict__ bt1,
    const float* __restrict__ gt, const float* __restrict__ blt,
    const unsigned short* __restrict__ Wt2T, const float* __restrict__ bt2,
    const unsigned short* __restrict__ Ws1T, const float* __restrict__ bs1,
    const float* __restrict__ gs, const float* __restrict__ bls,
    const unsigned short* __restrict__ Ws2T, const float* __restrict__ bs2,
    float* __restrict__ fs)
{
  const int tid = threadIdx.x;
  const int lane = tid & 63, w = tid >> 6;
  const int wm = w & 1, wn = w >> 1;       // 2 x 4 wave grid over 128 x 256
  const int fr = lane & 15, fg = lane >> 4;
  const int row0 = blockIdx.x * 128;

  __shared__ __align__(16) unsigned short lds_h[128 * 264];
  __shared__ __align__(16) unsigned short lds_a[128 * 72];
  __shared__ __align__(16) unsigned short lds_b[256 * 72];
  __shared__ float sb1[256], sg[256], sbe[256];
  __shared__ float red[128 * 8];
  __shared__ float lg[128 * 16];

  for (int head = 0; head < 2; ++head) {
    const unsigned short* W1T = head ? Ws1T : Wt1T;
    const unsigned short* W2T = head ? Ws2T : Wt2T;
    const float* b1 = head ? bs1 : bt1;
    const float* g  = head ? gs  : gt;
    const float* be = head ? bls : blt;
    const float* b2 = head ? bs2 : bt2;
    const int C2 = head ? 8 : 6;

    if (tid < 256) { sb1[tid] = b1[tid]; sg[tid] = g[tid]; sbe[tid] = be[tid]; }

    f32x4 acc[4][4];
#pragma unroll
    for (int i = 0; i < 4; ++i)
#pragma unroll
      for (int j = 0; j < 4; ++j) acc[i][j] = f32x4{0.f, 0.f, 0.f, 0.f};

    for (int kt = 0; kt < 4; ++kt) {
      __syncthreads();
      // stage A: x rows row0.., cols kt*64.. (fp32 -> bf16)
#pragma unroll
      for (int p = 0; p < 4; ++p) {
        int idx = tid + p * 512;
        int r = idx >> 4, c4 = idx & 15;
        float4 v = *(const float4*)&x[(size_t)(row0 + r) * DD + kt * 64 + c4 * 4];
        uint2 pk;
        pk.x = (unsigned)f2bf(v.x) | ((unsigned)f2bf(v.y) << 16);
        pk.y = (unsigned)f2bf(v.z) | ((unsigned)f2bf(v.w) << 16);
        *(uint2*)&lds_a[r * 72 + c4 * 4] = pk;
      }
      // stage B: W1T rows (output col), k-slice
#pragma unroll
      for (int p = 0; p < 4; ++p) {
        int idx = tid + p * 512;
        int r = idx >> 3, d4 = idx & 7;
        *(uint2*)&lds_b[r * 72 + d4 * 4] = *(const uint2*)&W1T[r * 256 + kt * 64 + d4 * 4];
      }
      __syncthreads();
#pragma unroll
      for (int ks = 0; ks < 2; ++ks) {
        s16x8 af[4], bfv[4];
#pragma unroll
        for (int i = 0; i < 4; ++i)
          af[i] = *(const s16x8*)&lds_a[(wm * 64 + i * 16 + fr) * 72 + ks * 32 + fg * 8];
#pragma unroll
        for (int j = 0; j < 4; ++j)
          bfv[j] = *(const s16x8*)&lds_b[(wn * 64 + j * 16 + fr) * 72 + ks * 32 + fg * 8];
#pragma unroll
        for (int i = 0; i < 4; ++i)
#pragma unroll
          for (int j = 0; j < 4; ++j)
            acc[i][j] = __builtin_amdgcn_mfma_f32_16x16x32_bf16(as_bf(af[i]), as_bf(bfv[j]), acc[i][j], 0, 0, 0);
      }
    }

    // bias + exact GELU in-place; per-row partial sums
    float sA[16], qA[16];
#pragma unroll
    for (int k = 0; k < 16; ++k) { sA[k] = 0.f; qA[k] = 0.f; }
#pragma unroll
    for (int i = 0; i < 4; ++i)
#pragma unroll
      for (int j = 0; j < 4; ++j) {
        int col = wn * 64 + j * 16 + fr;
        float bb = sb1[col];
#pragma unroll
        for (int r = 0; r < 4; ++r) {
          float h = acc[i][j][r] + bb;
          h = 0.5f * h * (1.0f + erff(h * 0.70710678118654752f));
          acc[i][j][r] = h;
          sA[i * 4 + r] += h;
          qA[i * 4 + r] += h * h;
        }
      }
    // reduce across the 16 lanes sharing the same rows (xor fr bits)
#pragma unroll
    for (int o = 1; o < 16; o <<= 1) {
#pragma unroll
      for (int k = 0; k < 16; ++k) {
        sA[k] += __shfl_xor(sA[k], o);
        qA[k] += __shfl_xor(qA[k], o);
      }
    }
    __syncthreads();
    if (fr == 0) {
#pragma unroll
      for (int i = 0; i < 4; ++i)
#pragma unroll
        for (int r = 0; r < 4; ++r) {
          int row = wm * 64 + i * 16 + fg * 4 + r;
          red[row * 8 + wn]     = sA[i * 4 + r];
          red[row * 8 + 4 + wn] = qA[i * 4 + r];
        }
    }
    __syncthreads();
    // LN normalize + affine -> lds_h (bf16)
#pragma unroll
    for (int i = 0; i < 4; ++i)
#pragma unroll
      for (int r = 0; r < 4; ++r) {
        int row = wm * 64 + i * 16 + fg * 4 + r;
        float s = red[row * 8 + 0] + red[row * 8 + 1] + red[row * 8 + 2] + red[row * 8 + 3];
        float q = red[row * 8 + 4] + red[row * 8 + 5] + red[row * 8 + 6] + red[row * 8 + 7];
        float mu = s * (1.0f / DD);
        float var = q * (1.0f / DD) - mu * mu;
        float rstd = rsqrtf(var + 1e-5f);
#pragma unroll
        for (int j = 0; j < 4; ++j) {
          int col = wn * 64 + j * 16 + fr;
          float hn = (acc[i][j][r] - mu) * rstd * sg[col] + sbe[col];
          lds_h[row * 264 + col] = f2bf(hn);
        }
      }
    __syncthreads();
    // stage W2T (16 x 256, zero-padded) into lds_b with LD 264
#pragma unroll
    for (int p = 0; p < 2; ++p) {
      int idx = tid + p * 512;  // 0..1023
      int r = idx >> 6, c4 = idx & 63;
      *(uint2*)&lds_b[r * 264 + c4 * 4] = *(const uint2*)&W2T[r * 256 + c4 * 4];
    }
    __syncthreads();
    // phase C: wave w handles rows w*16..w*16+15
    {
      f32x4 a1 = f32x4{0.f, 0.f, 0.f, 0.f};
#pragma unroll
      for (int ks = 0; ks < 8; ++ks) {
        s16x8 av = *(const s16x8*)&lds_h[(w * 16 + fr) * 264 + ks * 32 + fg * 8];
        s16x8 bv = *(const s16x8*)&lds_b[fr * 264 + ks * 32 + fg * 8];
        a1 = __builtin_amdgcn_mfma_f32_16x16x32_bf16(as_bf(av), as_bf(bv), a1, 0, 0, 0);
      }
#pragma unroll
      for (int r = 0; r < 4; ++r) lg[(w * 16 + fg * 4 + r) * 16 + fr] = a1[r];
    }
    __syncthreads();
    // loss
    if (tid < 128) {
      int grow = row0 + tid;
      int mbit = msk[grow];
      float contrib = 0.0f;
      if (head == 0) {
        float l[6], mx = -1e30f;
#pragma unroll
        for (int c = 0; c < 6; ++c) { l[c] = lg[tid * 16 + c] + b2[c]; mx = fmaxf(mx, l[c]); }
        float se = 0.0f;
#pragma unroll
        for (int c = 0; c < 6; ++c) se += expf(l[c] - mx);
        float lse = mx + logf(se);
        int t = tgt[grow];
        float lt = 0.0f;
#pragma unroll
        for (int c = 0; c < 6; ++c) lt = (c == t) ? l[c] : lt;
        contrib = mbit ? (lse - lt) : 0.0f;
      } else {
        const float* st = stats + (size_t)grow * 8;
        float sse = 0.0f;
#pragma unroll
        for (int c = 0; c < 8; ++c) {
          float d = (lg[tid * 16 + c] + b2[c]) - st[c];
          sse += d * d;
        }
        contrib = mbit ? sse : 0.0f;
      }
      float s = wave_sum(contrib);
      if ((tid & 63) == 0) atomicAdd(&fs[head], s);
    }
    __syncthreads();
  }
}

// ---------------- correlation: (b, 128-row i-tile) per block, MFMA ----------------
__global__ __launch_bounds__(512) void k_corr(
    const float* __restrict__ x, const int* __restrict__ msk,
    const float* __restrict__ corr, const unsigned short* __restrict__ WcT,
    const float* __restrict__ bcp, float* __restrict__ fs)
{
  const int tid = threadIdx.x;
  const int b  = blockIdx.x >> 2;
  const int it = blockIdx.x & 3;
  const int i0 = it * 128;
  const int lane = tid & 63, w = tid >> 6;
  const int wm = w & 1, wn = w >> 1;       // 2 x 4 wave grid
  const int fr = lane & 15, fg = lane >> 4;

  __shared__ __align__(16) unsigned short lds_y[128 * 264];
  __shared__ __align__(16) unsigned short lds_a[128 * 72];
  __shared__ __align__(16) unsigned short lds_b[256 * 72];
  __shared__ int ms_i[128];
  __shared__ int ms_j[256];
  __shared__ float red[8];

  const float* xb = x + (size_t)b * NN * DD;

  // ---- phase Y: y = x[i0..i0+127] @ Wc ----
  f32x4 acc[4][4];
#pragma unroll
  for (int i = 0; i < 4; ++i)
#pragma unroll
    for (int j = 0; j < 4; ++j) acc[i][j] = f32x4{0.f, 0.f, 0.f, 0.f};

  for (int kt = 0; kt < 4; ++kt) {
    __syncthreads();
#pragma unroll
    for (int p = 0; p < 4; ++p) {
      int idx = tid + p * 512;
      int r = idx >> 4, c4 = idx & 15;
      float4 v = *(const float4*)&xb[(size_t)(i0 + r) * DD + kt * 64 + c4 * 4];
      uint2 pk;
      pk.x = (unsigned)f2bf(v.x) | ((unsigned)f2bf(v.y) << 16);
      pk.y = (unsigned)f2bf(v.z) | ((unsigned)f2bf(v.w) << 16);
      *(uint2*)&lds_a[r * 72 + c4 * 4] = pk;
    }
#pragma unroll
    for (int p = 0; p < 4; ++p) {
      int idx = tid + p * 512;
      int r = idx >> 3, d4 = idx & 7;
      *(uint2*)&lds_b[r * 72 + d4 * 4] = *(const uint2*)&WcT[r * 256 + kt * 64 + d4 * 4];
    }
    __syncthreads();
#pragma unroll
    for (int ks = 0; ks < 2; ++ks) {
      s16x8 af[4], bfv[4];
#pragma unroll
      for (int i = 0; i < 4; ++i)
        af[i] = *(const s16x8*)&lds_a[(wm * 64 + i * 16 + fr) * 72 + ks * 32 + fg * 8];
#pragma unroll
      for (int j = 0; j < 4; ++j)
        bfv[j] = *(const s16x8*)&lds_b[(wn * 64 + j * 16 + fr) * 72 + ks * 32 + fg * 8];
#pragma unroll
      for (int i = 0; i < 4; ++i)
#pragma unroll
        for (int j = 0; j < 4; ++j)
          acc[i][j] = __builtin_amdgcn_mfma_f32_16x16x32_bf16(as_bf(af[i]), as_bf(bfv[j]), acc[i][j], 0, 0, 0);
    }
  }
  // write y tile (bf16) to lds_y; stage i-masks
#pragma unroll
  for (int i = 0; i < 4; ++i)
#pragma unroll
    for (int j = 0; j < 4; ++j)
#pragma unroll
      for (int r = 0; r < 4; ++r) {
        int row = wm * 64 + i * 16 + fg * 4 + r;
        int col = wn * 64 + j * 16 + fr;
        lds_y[row * 264 + col] = f2bf(acc[i][j][r]);
      }
  if (tid < 128) ms_i[tid] = msk[b * NN + i0 + tid];

  // ---- phase S: scores = y @ x^T, fused tanh + masked MSE ----
  const float bc = bcp[0];
  float sse = 0.0f;

  for (int jc = 0; jc < 2; ++jc) {
    const int j0 = jc * 256;
#pragma unroll
    for (int i = 0; i < 4; ++i)
#pragma unroll
      for (int j = 0; j < 4; ++j) acc[i][j] = f32x4{0.f, 0.f, 0.f, 0.f};

    for (int kt = 0; kt < 4; ++kt) {
      __syncthreads();
#pragma unroll
      for (int p = 0; p < 8; ++p) {
        int idx = tid + p * 512;
        int r = idx >> 4, c4 = idx & 15;
        float4 v = *(const float4*)&xb[(size_t)(j0 + r) * DD + kt * 64 + c4 * 4];
        uint2 pk;
        pk.x = (unsigned)f2bf(v.x) | ((unsigned)f2bf(v.y) << 16);
        pk.y = (unsigned)f2bf(v.z) | ((unsigned)f2bf(v.w) << 16);
        *(uint2*)&lds_b[r * 72 + c4 * 4] = pk;
      }
      if (kt == 0 && tid < 256) ms_j[tid] = msk[b * NN + j0 + tid];
      __syncthreads();
#pragma unroll
      for (int ks = 0; ks < 2; ++ks) {
        s16x8 af[4], bfv[4];
#pragma unroll
        for (int i = 0; i < 4; ++i)
          af[i] = *(const s16x8*)&lds_y[(wm * 64 + i * 16 + fr) * 264 + kt * 64 + ks * 32 + fg * 8];
#pragma unroll
        for (int j = 0; j < 4; ++j)
          bfv[j] = *(const s16x8*)&lds_b[(wn * 64 + j * 16 + fr) * 72 + ks * 32 + fg * 8];
#pragma unroll
        for (int i = 0; i < 4; ++i)
#pragma unroll
          for (int j = 0; j < 4; ++j)
            acc[i][j] = __builtin_amdgcn_mfma_f32_16x16x32_bf16(as_bf(af[i]), as_bf(bfv[j]), acc[i][j], 0, 0, 0);
      }
    }
    // epilogue: tanh + masked MSE vs targets
    const float* tb = corr + (size_t)b * NN * NN;
#pragma unroll
    for (int i = 0; i < 4; ++i) {
      int rbase = wm * 64 + i * 16 + fg * 4;
#pragma unroll
      for (int j = 0; j < 4; ++j) {
        int colc = wn * 64 + j * 16 + fr;
        int gj = j0 + colc;
        int mj = ms_j[colc];
#pragma unroll
        for (int r = 0; r < 4; ++r) {
          int gi = i0 + rbase + r;
          float s = acc[i][j][r] + bc;
          float e = __expf(2.0f * s);
          float cv = 1.0f - 2.0f * __builtin_amdgcn_rcpf(e + 1.0f);
          if (gi == gj) cv = 1.0f;
          float tg = tb[(size_t)gi * NN + gj];
          float d = cv - tg;
          int mb = ms_i[rbase + r] | mj;
          sse += mb ? d * d : 0.0f;
        }
      }
    }
  }

  float s = wave_sum(sse);
  if (lane == 0) red[w] = s;
  __syncthreads();
  if (tid == 0) {
    float t = 0.f;
#pragma unroll
    for (int i = 0; i < 8; ++i) t += red[i];
    atomicAdd(&fs[2], t);
  }
}

__global__ void k_final(const float* __restrict__ fs, const int* __restrict__ wsi,
                        float* __restrict__ out) {
  if (threadIdx.x == 0 && blockIdx.x == 0) {
    float cm = (float)wsi[4];
    float c2 = (float)wsi[5];
    out[0] = fs[0] / fmaxf(cm, 1.0f) + fs[1] / fmaxf(8.0f * cm, 1.0f) +
             0.5f * fs[2] / fmaxf(c2, 1.0f);
  }
}

extern "C" void kernel_launch(void* const* d_in, const int* in_sizes, int n_in,
                              void* d_out, int out_size, void* d_ws, size_t ws_size,
                              hipStream_t stream) {
  const float* x     = (const float*)d_in[0];
  const int*   msk   = (const int*)d_in[1];
  const int*   tgt   = (const int*)d_in[2];
  const float* stats = (const float*)d_in[3];
  const float* corr  = (const float*)d_in[4];
  const float* Wt1   = (const float*)d_in[5];
  const float* bt1   = (const float*)d_in[6];
  const float* gt    = (const float*)d_in[7];
  const float* blt   = (const float*)d_in[8];
  const float* Wt2   = (const float*)d_in[9];
  const float* bt2   = (const float*)d_in[10];
  const float* Ws1   = (const float*)d_in[11];
  const float* bs1   = (const float*)d_in[12];
  const float* gs    = (const float*)d_in[13];
  const float* bls   = (const float*)d_in[14];
  const float* Ws2   = (const float*)d_in[15];
  const float* bs2   = (const float*)d_in[16];
  const float* Wc    = (const float*)d_in[17];
  const float* bc    = (const float*)d_in[18];

  float* fs = (float*)d_ws;
  int* wsi  = (int*)d_ws;
  unsigned short* WcT  = (unsigned short*)((char*)d_ws + 256);
  unsigned short* Wt1T = WcT + 65536;
  unsigned short* Ws1T = Wt1T + 65536;
  unsigned short* Wt2T = Ws1T + 65536;
  unsigned short* Ws2T = Wt2T + 4096;

  hipLaunchKernelGGL(k_init, dim3(1), dim3(64), 0, stream, wsi);
  hipLaunchKernelGGL(k_counts, dim3(BB), dim3(256), 0, stream, msk, wsi);
  hipLaunchKernelGGL(k_prep, dim3(256), dim3(256), 0, stream,
                     Wc, Wt1, Ws1, Wt2, Ws2, WcT, Wt1T, Ws1T, Wt2T, Ws2T);
  hipLaunchKernelGGL(k_heads, dim3((BB * NN) / 128), dim3(512), 0, stream,
                     x, msk, tgt, stats, Wt1T, bt1, gt, blt, Wt2T, bt2,
                     Ws1T, bs1, gs, bls, Ws2T, bs2, fs);
  hipLaunchKernelGGL(k_corr, dim3(BB * (NN / 128)), dim3(512), 0, stream,
                     x, msk, corr, WcT, bc, fs);
  hipLaunchKernelGGL(k_final, dim3(1), dim3(64), 0, stream, fs, wsi, (float*)d_out);
}

// Round 5
// 200.846 us; speedup vs baseline: 5.6167x; 1.2129x over previous
//
#include <hip/hip_runtime.h>
#include <hip/hip_bf16.h>

#define BB 128
#define NN 512
#define DD 256

typedef __attribute__((ext_vector_type(4))) float f32x4;
typedef __attribute__((ext_vector_type(8))) short s16x8;
typedef __attribute__((ext_vector_type(8))) __bf16 bf16x8;

static __device__ __forceinline__ bf16x8 as_bf(s16x8 v) {
  return __builtin_bit_cast(bf16x8, v);
}

static __device__ __forceinline__ unsigned short f2bf(float f) {
  unsigned u = __builtin_bit_cast(unsigned, f);
  u += 0x7FFFu + ((u >> 16) & 1u);
  return (unsigned short)(u >> 16);
}

__device__ __forceinline__ float wave_sum(float v) {
#pragma unroll
  for (int o = 32; o > 0; o >>= 1) v += __shfl_xor(v, o);
  return v;
}

__global__ void k_init(int* wsi) {
  if (threadIdx.x < 8) wsi[threadIdx.x] = 0;
}

__global__ void k_counts(const int* __restrict__ msk, int* __restrict__ wsi) {
  const int b = blockIdx.x;
  int cnt = 0;
  for (int i = threadIdx.x; i < NN; i += blockDim.x) cnt += (msk[b * NN + i] != 0) ? 1 : 0;
  float s = wave_sum((float)cnt);
  __shared__ float red[4];
  const int lane = threadIdx.x & 63, wv = threadIdx.x >> 6;
  if (lane == 0) red[wv] = s;
  __syncthreads();
  if (threadIdx.x == 0) {
    int k = (int)(red[0] + red[1] + red[2] + red[3] + 0.5f);
    atomicAdd(&wsi[4], k);
    atomicAdd(&wsi[5], NN * NN - (NN - k) * (NN - k));
  }
}

// transpose + bf16-convert the weight matrices into workspace
__global__ void k_prep(const float* __restrict__ Wc, const float* __restrict__ Wt1,
                       const float* __restrict__ Ws1, const float* __restrict__ Wt2,
                       const float* __restrict__ Ws2,
                       unsigned short* __restrict__ WcT, unsigned short* __restrict__ Wt1T,
                       unsigned short* __restrict__ Ws1T, unsigned short* __restrict__ Wt2T,
                       unsigned short* __restrict__ Ws2T) {
  int t = blockIdx.x * 256 + threadIdx.x;  // 0..65535
  int c = t >> 8, d = t & 255;
  WcT [c * 256 + d] = f2bf(Wc [d * 256 + c]);
  Wt1T[c * 256 + d] = f2bf(Wt1[d * 256 + c]);
  Ws1T[c * 256 + d] = f2bf(Ws1[d * 256 + c]);
  if (c < 16) {
    Wt2T[c * 256 + d] = (c < 6) ? f2bf(Wt2[d * 6 + c]) : (unsigned short)0;
    Ws2T[c * 256 + d] = (c < 8) ? f2bf(Ws2[d * 8 + c]) : (unsigned short)0;
  }
}

// ---------------- heads: 128 rows/block, 512 threads, dual-head fused K-loop ----------------
// Round-2 frame (proven): 2x4 wave grid, separate LDS buffers, plain launch_bounds.
// Deltas vs round 2: full-width uint4 W staging; x staged ONCE for both heads (at/asx accs).
__global__ __launch_bounds__(512) void k_heads(
    const float* __restrict__ x, const int* __restrict__ msk,
    const int* __restrict__ tgt, const float* __restrict__ stats,
    const unsigned short* __restrict__ Wt1T, const unsigned short* __restrict__ Ws1T,
    const unsigned short* __restrict__ Wt2T, const unsigned short* __restrict__ Ws2T,
    const float* __restrict__ bt1, const float* __restrict__ bs1,
    const float* __restrict__ gt, const float* __restrict__ gs,
    const float* __restrict__ blt, const float* __restrict__ bls,
    const float* __restrict__ bt2, const float* __restrict__ bs2,
    float* __restrict__ fs)
{
  const int tid = threadIdx.x;
  const int lane = tid & 63, w = tid >> 6;
  const int wm = w & 1, wn = w >> 1;       // 2 x 4 wave grid over 128 x 256
  const int fr = lane & 15, fg = lane >> 4;
  const int row0 = blockIdx.x * 128;

  __shared__ __align__(16) unsigned short lds_h[128 * 264];
  __shared__ __align__(16) unsigned short lds_a[128 * 72];
  __shared__ __align__(16) unsigned short lds_b[256 * 72];
  __shared__ float sb1[2][256], sg[2][256], sbe[2][256];
  __shared__ float red[128 * 8];
  __shared__ float lg[128 * 16];

  if (tid < 256) { sb1[0][tid] = bt1[tid]; sg[0][tid] = gt[tid]; sbe[0][tid] = blt[tid]; }
  else { int t = tid - 256; sb1[1][t] = bs1[t]; sg[1][t] = gs[t]; sbe[1][t] = bls[t]; }

  f32x4 at[4][4], asx[4][4];
#pragma unroll
  for (int i = 0; i < 4; ++i)
#pragma unroll
    for (int j = 0; j < 4; ++j) {
      at[i][j]  = f32x4{0.f, 0.f, 0.f, 0.f};
      asx[i][j] = f32x4{0.f, 0.f, 0.f, 0.f};
    }

  for (int kt = 0; kt < 4; ++kt) {
    __syncthreads();
    // stage A: x rows row0.., cols kt*64.. (fp32 -> bf16), full 128x64
#pragma unroll
    for (int p = 0; p < 4; ++p) {
      int idx = tid + p * 512;
      int r = idx >> 4, c4 = idx & 15;
      float4 v = *(const float4*)&x[(size_t)(row0 + r) * DD + kt * 64 + c4 * 4];
      uint2 pk;
      pk.x = (unsigned)f2bf(v.x) | ((unsigned)f2bf(v.y) << 16);
      pk.y = (unsigned)f2bf(v.z) | ((unsigned)f2bf(v.w) << 16);
      *(uint2*)&lds_a[r * 72 + c4 * 4] = pk;
    }
    // stage B: Wt1T slice, FULL width (256 rows x 64 shorts, uint4 = 8 shorts/chunk)
#pragma unroll
    for (int p = 0; p < 4; ++p) {
      int idx = tid + p * 512;
      int r = idx >> 3, ch = idx & 7;
      *(uint4*)&lds_b[r * 72 + ch * 8] = *(const uint4*)&Wt1T[r * 256 + kt * 64 + ch * 8];
    }
    __syncthreads();
#pragma unroll
    for (int ks = 0; ks < 2; ++ks) {
      s16x8 af[4], bfv[4];
#pragma unroll
      for (int i = 0; i < 4; ++i)
        af[i] = *(const s16x8*)&lds_a[(wm * 64 + i * 16 + fr) * 72 + ks * 32 + fg * 8];
#pragma unroll
      for (int j = 0; j < 4; ++j)
        bfv[j] = *(const s16x8*)&lds_b[(wn * 64 + j * 16 + fr) * 72 + ks * 32 + fg * 8];
#pragma unroll
      for (int i = 0; i < 4; ++i)
#pragma unroll
        for (int j = 0; j < 4; ++j)
          at[i][j] = __builtin_amdgcn_mfma_f32_16x16x32_bf16(as_bf(af[i]), as_bf(bfv[j]), at[i][j], 0, 0, 0);
    }
    __syncthreads();
    // restage B with Ws1T slice (x stays in lds_a — read once, used twice)
#pragma unroll
    for (int p = 0; p < 4; ++p) {
      int idx = tid + p * 512;
      int r = idx >> 3, ch = idx & 7;
      *(uint4*)&lds_b[r * 72 + ch * 8] = *(const uint4*)&Ws1T[r * 256 + kt * 64 + ch * 8];
    }
    __syncthreads();
#pragma unroll
    for (int ks = 0; ks < 2; ++ks) {
      s16x8 af[4], bfv[4];
#pragma unroll
      for (int i = 0; i < 4; ++i)
        af[i] = *(const s16x8*)&lds_a[(wm * 64 + i * 16 + fr) * 72 + ks * 32 + fg * 8];
#pragma unroll
      for (int j = 0; j < 4; ++j)
        bfv[j] = *(const s16x8*)&lds_b[(wn * 64 + j * 16 + fr) * 72 + ks * 32 + fg * 8];
#pragma unroll
      for (int i = 0; i < 4; ++i)
#pragma unroll
        for (int j = 0; j < 4; ++j)
          asx[i][j] = __builtin_amdgcn_mfma_f32_16x16x32_bf16(as_bf(af[i]), as_bf(bfv[j]), asx[i][j], 0, 0, 0);
    }
  }

  // ===================== head 0 epilogue (round-2 proven, acc = at) =====================
  {
    float sA[16], qA[16];
#pragma unroll
    for (int k = 0; k < 16; ++k) { sA[k] = 0.f; qA[k] = 0.f; }
#pragma unroll
    for (int i = 0; i < 4; ++i)
#pragma unroll
      for (int j = 0; j < 4; ++j) {
        int col = wn * 64 + j * 16 + fr;
        float bb = sb1[0][col];
#pragma unroll
        for (int r = 0; r < 4; ++r) {
          float h = at[i][j][r] + bb;
          h = 0.5f * h * (1.0f + erff(h * 0.70710678118654752f));
          at[i][j][r] = h;
          sA[i * 4 + r] += h;
          qA[i * 4 + r] += h * h;
        }
      }
#pragma unroll
    for (int o = 1; o < 16; o <<= 1) {
#pragma unroll
      for (int k = 0; k < 16; ++k) {
        sA[k] += __shfl_xor(sA[k], o);
        qA[k] += __shfl_xor(qA[k], o);
      }
    }
    __syncthreads();
    if (fr == 0) {
#pragma unroll
      for (int i = 0; i < 4; ++i)
#pragma unroll
        for (int r = 0; r < 4; ++r) {
          int row = wm * 64 + i * 16 + fg * 4 + r;
          red[row * 8 + wn]     = sA[i * 4 + r];
          red[row * 8 + 4 + wn] = qA[i * 4 + r];
        }
    }
    __syncthreads();
#pragma unroll
    for (int i = 0; i < 4; ++i)
#pragma unroll
      for (int r = 0; r < 4; ++r) {
        int row = wm * 64 + i * 16 + fg * 4 + r;
        float s = red[row * 8 + 0] + red[row * 8 + 1] + red[row * 8 + 2] + red[row * 8 + 3];
        float q = red[row * 8 + 4] + red[row * 8 + 5] + red[row * 8 + 6] + red[row * 8 + 7];
        float mu = s * (1.0f / DD);
        float var = q * (1.0f / DD) - mu * mu;
        float rstd = rsqrtf(var + 1e-5f);
#pragma unroll
        for (int j = 0; j < 4; ++j) {
          int col = wn * 64 + j * 16 + fr;
          float hn = (at[i][j][r] - mu) * rstd * sg[0][col] + sbe[0][col];
          lds_h[row * 264 + col] = f2bf(hn);
        }
      }
    __syncthreads();
#pragma unroll
    for (int p = 0; p < 2; ++p) {
      int idx = tid + p * 512;
      int r = idx >> 6, c4 = idx & 63;
      *(uint2*)&lds_b[r * 264 + c4 * 4] = *(const uint2*)&Wt2T[r * 256 + c4 * 4];
    }
    __syncthreads();
    {
      f32x4 a1 = f32x4{0.f, 0.f, 0.f, 0.f};
#pragma unroll
      for (int ks = 0; ks < 8; ++ks) {
        s16x8 av = *(const s16x8*)&lds_h[(w * 16 + fr) * 264 + ks * 32 + fg * 8];
        s16x8 bv = *(const s16x8*)&lds_b[fr * 264 + ks * 32 + fg * 8];
        a1 = __builtin_amdgcn_mfma_f32_16x16x32_bf16(as_bf(av), as_bf(bv), a1, 0, 0, 0);
      }
#pragma unroll
      for (int r = 0; r < 4; ++r) lg[(w * 16 + fg * 4 + r) * 16 + fr] = a1[r];
    }
    __syncthreads();
    if (tid < 128) {
      int grow = row0 + tid;
      int mbit = msk[grow];
      float contrib = 0.0f;
      float l[6], mx = -1e30f;
#pragma unroll
      for (int c = 0; c < 6; ++c) { l[c] = lg[tid * 16 + c] + bt2[c]; mx = fmaxf(mx, l[c]); }
      float se = 0.0f;
#pragma unroll
      for (int c = 0; c < 6; ++c) se += expf(l[c] - mx);
      float lse = mx + logf(se);
      int t = tgt[grow];
      float lt = 0.0f;
#pragma unroll
      for (int c = 0; c < 6; ++c) lt = (c == t) ? l[c] : lt;
      contrib = mbit ? (lse - lt) : 0.0f;
      float s = wave_sum(contrib);
      if ((tid & 63) == 0) atomicAdd(&fs[0], s);
    }
    __syncthreads();
  }

  // ===================== head 1 epilogue (same code, acc = asx) =====================
  {
    float sA[16], qA[16];
#pragma unroll
    for (int k = 0; k < 16; ++k) { sA[k] = 0.f; qA[k] = 0.f; }
#pragma unroll
    for (int i = 0; i < 4; ++i)
#pragma unroll
      for (int j = 0; j < 4; ++j) {
        int col = wn * 64 + j * 16 + fr;
        float bb = sb1[1][col];
#pragma unroll
        for (int r = 0; r < 4; ++r) {
          float h = asx[i][j][r] + bb;
          h = 0.5f * h * (1.0f + erff(h * 0.70710678118654752f));
          asx[i][j][r] = h;
          sA[i * 4 + r] += h;
          qA[i * 4 + r] += h * h;
        }
      }
#pragma unroll
    for (int o = 1; o < 16; o <<= 1) {
#pragma unroll
      for (int k = 0; k < 16; ++k) {
        sA[k] += __shfl_xor(sA[k], o);
        qA[k] += __shfl_xor(qA[k], o);
      }
    }
    __syncthreads();
    if (fr == 0) {
#pragma unroll
      for (int i = 0; i < 4; ++i)
#pragma unroll
        for (int r = 0; r < 4; ++r) {
          int row = wm * 64 + i * 16 + fg * 4 + r;
          red[row * 8 + wn]     = sA[i * 4 + r];
          red[row * 8 + 4 + wn] = qA[i * 4 + r];
        }
    }
    __syncthreads();
#pragma unroll
    for (int i = 0; i < 4; ++i)
#pragma unroll
      for (int r = 0; r < 4; ++r) {
        int row = wm * 64 + i * 16 + fg * 4 + r;
        float s = red[row * 8 + 0] + red[row * 8 + 1] + red[row * 8 + 2] + red[row * 8 + 3];
        float q = red[row * 8 + 4] + red[row * 8 + 5] + red[row * 8 + 6] + red[row * 8 + 7];
        float mu = s * (1.0f / DD);
        float var = q * (1.0f / DD) - mu * mu;
        float rstd = rsqrtf(var + 1e-5f);
#pragma unroll
        for (int j = 0; j < 4; ++j) {
          int col = wn * 64 + j * 16 + fr;
          float hn = (asx[i][j][r] - mu) * rstd * sg[1][col] + sbe[1][col];
          lds_h[row * 264 + col] = f2bf(hn);
        }
      }
    __syncthreads();
#pragma unroll
    for (int p = 0; p < 2; ++p) {
      int idx = tid + p * 512;
      int r = idx >> 6, c4 = idx & 63;
      *(uint2*)&lds_b[r * 264 + c4 * 4] = *(const uint2*)&Ws2T[r * 256 + c4 * 4];
    }
    __syncthreads();
    {
      f32x4 a1 = f32x4{0.f, 0.f, 0.f, 0.f};
#pragma unroll
      for (int ks = 0; ks < 8; ++ks) {
        s16x8 av = *(const s16x8*)&lds_h[(w * 16 + fr) * 264 + ks * 32 + fg * 8];
        s16x8 bv = *(const s16x8*)&lds_b[fr * 264 + ks * 32 + fg * 8];
        a1 = __builtin_amdgcn_mfma_f32_16x16x32_bf16(as_bf(av), as_bf(bv), a1, 0, 0, 0);
      }
#pragma unroll
      for (int r = 0; r < 4; ++r) lg[(w * 16 + fg * 4 + r) * 16 + fr] = a1[r];
    }
    __syncthreads();
    if (tid < 128) {
      int grow = row0 + tid;
      int mbit = msk[grow];
      const float* st = stats + (size_t)grow * 8;
      float sse = 0.0f;
#pragma unroll
      for (int c = 0; c < 8; ++c) {
        float d = (lg[tid * 16 + c] + bs2[c]) - st[c];
        sse += d * d;
      }
      float contrib = mbit ? sse : 0.0f;
      float s = wave_sum(contrib);
      if ((tid & 63) == 0) atomicAdd(&fs[1], s);
    }
  }
}

// ---------------- correlation: (b, 128-row i-tile) per block, MFMA ----------------
__global__ __launch_bounds__(512) void k_corr(
    const float* __restrict__ x, const int* __restrict__ msk,
    const float* __restrict__ corr, const unsigned short* __restrict__ WcT,
    const float* __restrict__ bcp, float* __restrict__ fs)
{
  const int tid = threadIdx.x;
  const int b  = blockIdx.x >> 2;
  const int it = blockIdx.x & 3;
  const int i0 = it * 128;
  const int lane = tid & 63, w = tid >> 6;
  const int wm = w & 1, wn = w >> 1;       // 2 x 4 wave grid
  const int fr = lane & 15, fg = lane >> 4;

  __shared__ __align__(16) unsigned short lds_y[128 * 264];
  __shared__ __align__(16) unsigned short lds_a[128 * 72];
  __shared__ __align__(16) unsigned short lds_b[256 * 72];
  __shared__ int ms_i[128];
  __shared__ int ms_j[256];
  __shared__ float red[8];

  const float* xb = x + (size_t)b * NN * DD;

  // ---- phase Y: y = x[i0..i0+127] @ Wc ----
  f32x4 acc[4][4];
#pragma unroll
  for (int i = 0; i < 4; ++i)
#pragma unroll
    for (int j = 0; j < 4; ++j) acc[i][j] = f32x4{0.f, 0.f, 0.f, 0.f};

  for (int kt = 0; kt < 4; ++kt) {
    __syncthreads();
#pragma unroll
    for (int p = 0; p < 4; ++p) {
      int idx = tid + p * 512;
      int r = idx >> 4, c4 = idx & 15;
      float4 v = *(const float4*)&xb[(size_t)(i0 + r) * DD + kt * 64 + c4 * 4];
      uint2 pk;
      pk.x = (unsigned)f2bf(v.x) | ((unsigned)f2bf(v.y) << 16);
      pk.y = (unsigned)f2bf(v.z) | ((unsigned)f2bf(v.w) << 16);
      *(uint2*)&lds_a[r * 72 + c4 * 4] = pk;
    }
    // FULL-width WcT staging (uint4, 8 shorts/chunk)
#pragma unroll
    for (int p = 0; p < 4; ++p) {
      int idx = tid + p * 512;
      int r = idx >> 3, ch = idx & 7;
      *(uint4*)&lds_b[r * 72 + ch * 8] = *(const uint4*)&WcT[r * 256 + kt * 64 + ch * 8];
    }
    __syncthreads();
#pragma unroll
    for (int ks = 0; ks < 2; ++ks) {
      s16x8 af[4], bfv[4];
#pragma unroll
      for (int i = 0; i < 4; ++i)
        af[i] = *(const s16x8*)&lds_a[(wm * 64 + i * 16 + fr) * 72 + ks * 32 + fg * 8];
#pragma unroll
      for (int j = 0; j < 4; ++j)
        bfv[j] = *(const s16x8*)&lds_b[(wn * 64 + j * 16 + fr) * 72 + ks * 32 + fg * 8];
#pragma unroll
      for (int i = 0; i < 4; ++i)
#pragma unroll
        for (int j = 0; j < 4; ++j)
          acc[i][j] = __builtin_amdgcn_mfma_f32_16x16x32_bf16(as_bf(af[i]), as_bf(bfv[j]), acc[i][j], 0, 0, 0);
    }
  }
  // write y tile (bf16) to lds_y; stage i-masks
#pragma unroll
  for (int i = 0; i < 4; ++i)
#pragma unroll
    for (int j = 0; j < 4; ++j)
#pragma unroll
      for (int r = 0; r < 4; ++r) {
        int row = wm * 64 + i * 16 + fg * 4 + r;
        int col = wn * 64 + j * 16 + fr;
        lds_y[row * 264 + col] = f2bf(acc[i][j][r]);
      }
  if (tid < 128) ms_i[tid] = msk[b * NN + i0 + tid];

  // ---- phase S: scores = y @ x^T, fused tanh + masked MSE ----
  const float bc = bcp[0];
  float sse = 0.0f;

  for (int jc = 0; jc < 2; ++jc) {
    const int j0 = jc * 256;
#pragma unroll
    for (int i = 0; i < 4; ++i)
#pragma unroll
      for (int j = 0; j < 4; ++j) acc[i][j] = f32x4{0.f, 0.f, 0.f, 0.f};

    for (int kt = 0; kt < 4; ++kt) {
      __syncthreads();
#pragma unroll
      for (int p = 0; p < 8; ++p) {
        int idx = tid + p * 512;
        int r = idx >> 4, c4 = idx & 15;
        float4 v = *(const float4*)&xb[(size_t)(j0 + r) * DD + kt * 64 + c4 * 4];
        uint2 pk;
        pk.x = (unsigned)f2bf(v.x) | ((unsigned)f2bf(v.y) << 16);
        pk.y = (unsigned)f2bf(v.z) | ((unsigned)f2bf(v.w) << 16);
        *(uint2*)&lds_b[r * 72 + c4 * 4] = pk;
      }
      if (kt == 0 && tid < 256) ms_j[tid] = msk[b * NN + j0 + tid];
      __syncthreads();
#pragma unroll
      for (int ks = 0; ks < 2; ++ks) {
        s16x8 af[4], bfv[4];
#pragma unroll
        for (int i = 0; i < 4; ++i)
          af[i] = *(const s16x8*)&lds_y[(wm * 64 + i * 16 + fr) * 264 + kt * 64 + ks * 32 + fg * 8];
#pragma unroll
        for (int j = 0; j < 4; ++j)
          bfv[j] = *(const s16x8*)&lds_b[(wn * 64 + j * 16 + fr) * 72 + ks * 32 + fg * 8];
#pragma unroll
        for (int i = 0; i < 4; ++i)
#pragma unroll
          for (int j = 0; j < 4; ++j)
            acc[i][j] = __builtin_amdgcn_mfma_f32_16x16x32_bf16(as_bf(af[i]), as_bf(bfv[j]), acc[i][j], 0, 0, 0);
      }
    }
    // epilogue: tanh + masked MSE vs targets
    const float* tb = corr + (size_t)b * NN * NN;
#pragma unroll
    for (int i = 0; i < 4; ++i) {
      int rbase = wm * 64 + i * 16 + fg * 4;
#pragma unroll
      for (int j = 0; j < 4; ++j) {
        int colc = wn * 64 + j * 16 + fr;
        int gj = j0 + colc;
        int mj = ms_j[colc];
#pragma unroll
        for (int r = 0; r < 4; ++r) {
          int gi = i0 + rbase + r;
          float s = acc[i][j][r] + bc;
          float e = __expf(2.0f * s);
          float cv = 1.0f - 2.0f * __builtin_amdgcn_rcpf(e + 1.0f);
          if (gi == gj) cv = 1.0f;
          float tg = tb[(size_t)gi * NN + gj];
          float d = cv - tg;
          int mb = ms_i[rbase + r] | mj;
          sse += mb ? d * d : 0.0f;
        }
      }
    }
  }

  float s = wave_sum(sse);
  if (lane == 0) red[w] = s;
  __syncthreads();
  if (tid == 0) {
    float t = 0.f;
#pragma unroll
    for (int i = 0; i < 8; ++i) t += red[i];
    atomicAdd(&fs[2], t);
  }
}

__global__ void k_final(const float* __restrict__ fs, const int* __restrict__ wsi,
                        float* __restrict__ out) {
  if (threadIdx.x == 0 && blockIdx.x == 0) {
    float cm = (float)wsi[4];
    float c2 = (float)wsi[5];
    out[0] = fs[0] / fmaxf(cm, 1.0f) + fs[1] / fmaxf(8.0f * cm, 1.0f) +
             0.5f * fs[2] / fmaxf(c2, 1.0f);
  }
}

extern "C" void kernel_launch(void* const* d_in, const int* in_sizes, int n_in,
                              void* d_out, int out_size, void* d_ws, size_t ws_size,
                              hipStream_t stream) {
  const float* x     = (const float*)d_in[0];
  const int*   msk   = (const int*)d_in[1];
  const int*   tgt   = (const int*)d_in[2];
  const float* stats = (const float*)d_in[3];
  const float* corr  = (const float*)d_in[4];
  const float* Wt1   = (const float*)d_in[5];
  const float* bt1   = (const float*)d_in[6];
  const float* gt    = (const float*)d_in[7];
  const float* blt   = (const float*)d_in[8];
  const float* Wt2   = (const float*)d_in[9];
  const float* bt2   = (const float*)d_in[10];
  const float* Ws1   = (const float*)d_in[11];
  const float* bs1   = (const float*)d_in[12];
  const float* gs    = (const float*)d_in[13];
  const float* bls   = (const float*)d_in[14];
  const float* Ws2   = (const float*)d_in[15];
  const float* bs2   = (const float*)d_in[16];
  const float* Wc    = (const float*)d_in[17];
  const float* bc    = (const float*)d_in[18];

  float* fs = (float*)d_ws;
  int* wsi  = (int*)d_ws;
  unsigned short* WcT  = (unsigned short*)((char*)d_ws + 256);
  unsigned short* Wt1T = WcT + 65536;
  unsigned short* Ws1T = Wt1T + 65536;
  unsigned short* Wt2T = Ws1T + 65536;
  unsigned short* Ws2T = Wt2T + 4096;

  hipLaunchKernelGGL(k_init, dim3(1), dim3(64), 0, stream, wsi);
  hipLaunchKernelGGL(k_counts, dim3(BB), dim3(256), 0, stream, msk, wsi);
  hipLaunchKernelGGL(k_prep, dim3(256), dim3(256), 0, stream,
                     Wc, Wt1, Ws1, Wt2, Ws2, WcT, Wt1T, Ws1T, Wt2T, Ws2T);
  hipLaunchKernelGGL(k_heads, dim3((BB * NN) / 128), dim3(512), 0, stream,
                     x, msk, tgt, stats, Wt1T, Ws1T, Wt2T, Ws2T,
                     bt1, bs1, gt, gs, blt, bls, bt2, bs2, fs);
  hipLaunchKernelGGL(k_corr, dim3(BB * (NN / 128)), dim3(512), 0, stream,
                     x, msk, corr, WcT, bc, fs);
  hipLaunchKernelGGL(k_final, dim3(1), dim3(64), 0, stream, fs, wsi, (float*)d_out);
}